// Round 1
// baseline (493.622 us; speedup 1.0000x reference)
//
#include <hip/hip_runtime.h>

// V: (1, 80, 96, 112, 16) f32  ->  out: (1, 160, 192, 224, 16) f32
// Separable 2x linear upsample, edge clamp. even = copy, odd = avg(i, i+1).

#define DV 80
#define HV 96
#define WV 112
// C = 16 floats = 4 x float4 per voxel

__device__ __forceinline__ float4 avg4(float4 x, float4 y) {
    return make_float4(0.5f * (x.x + y.x), 0.5f * (x.y + y.y),
                       0.5f * (x.z + y.z), 0.5f * (x.w + y.w));
}

__global__ __launch_bounds__(448) void UpsampleInterp_kernel(
        const float4* __restrict__ in, float4* __restrict__ out) {
    const int ho  = blockIdx.x;            // 0..191
    const int dof = blockIdx.y;            // 0..159
    const int tx  = threadIdx.x;           // 0..447
    const int c4  = tx & 3;                // channel quad 0..3
    const int wi  = tx >> 2;               // 0..111

    const int d0  = dof >> 1;
    const int h0  = ho >> 1;
    const int wib = (wi + 1 < WV) ? wi + 1 : WV - 1;

    // float4 index: ((d*HV + h)*WV + w)*4 + c4
    const int rowstride = WV * 4;
    const int base00 = (d0 * HV + h0) * rowstride + c4;

    const bool dodd = dof & 1;   // block-uniform
    const bool hodd = ho & 1;    // block-uniform

    float4 a, b;  // d/h-interpolated values at w = wi and w = wib
    if (!dodd && !hodd) {
        a = in[base00 + wi * 4];
        b = in[base00 + wib * 4];
    } else if (!dodd) {  // h odd only
        const int h1 = (h0 + 1 < HV) ? h0 + 1 : HV - 1;
        const int base01 = (d0 * HV + h1) * rowstride + c4;
        a = avg4(in[base00 + wi * 4],  in[base01 + wi * 4]);
        b = avg4(in[base00 + wib * 4], in[base01 + wib * 4]);
    } else if (!hodd) {  // d odd only
        const int d1 = (d0 + 1 < DV) ? d0 + 1 : DV - 1;
        const int base10 = (d1 * HV + h0) * rowstride + c4;
        a = avg4(in[base00 + wi * 4],  in[base10 + wi * 4]);
        b = avg4(in[base00 + wib * 4], in[base10 + wib * 4]);
    } else {             // both odd: 4 corners in (d,h)
        const int d1 = (d0 + 1 < DV) ? d0 + 1 : DV - 1;
        const int h1 = (h0 + 1 < HV) ? h0 + 1 : HV - 1;
        const int base01 = (d0 * HV + h1) * rowstride + c4;
        const int base10 = (d1 * HV + h0) * rowstride + c4;
        const int base11 = (d1 * HV + h1) * rowstride + c4;
        a = avg4(avg4(in[base00 + wi * 4],  in[base10 + wi * 4]),
                 avg4(in[base01 + wi * 4],  in[base11 + wi * 4]));
        b = avg4(avg4(in[base00 + wib * 4], in[base10 + wib * 4]),
                 avg4(in[base01 + wib * 4], in[base11 + wib * 4]));
    }

    // output float4 index: ((dof*(2*HV) + ho)*(2*WV) + wo)*4 + c4
    const int obase = (dof * (2 * HV) + ho) * (2 * WV * 4) + c4;
    out[obase + (2 * wi) * 4]     = a;            // even wo: copy
    out[obase + (2 * wi + 1) * 4] = avg4(a, b);   // odd wo: average
}

extern "C" void kernel_launch(void* const* d_in, const int* in_sizes, int n_in,
                              void* d_out, int out_size, void* d_ws, size_t ws_size,
                              hipStream_t stream) {
    const float4* in = (const float4*)d_in[0];
    float4* out = (float4*)d_out;
    dim3 grid(2 * HV, 2 * DV);  // (ho, do) = (192, 160)
    UpsampleInterp_kernel<<<grid, 448, 0, stream>>>(in, out);
}

// Round 2
// 478.261 us; speedup vs baseline: 1.0321x; 1.0321x over previous
//
#include <hip/hip_runtime.h>

// V: (1, 80, 96, 112, 16) f32  ->  out: (1, 160, 192, 224, 16) f32
// Separable 2x linear upsample, edge clamp. even = copy, odd = avg(i, i+1).
//
// Block = one input (d0,h0) site -> output row-quad {2d0,2d0+1} x {2h0,2h0+1}.
// 896 threads; thread t owns output float4 column t of each of the 4 rows, so
// every store instruction is perfectly contiguous (1024 B / wave).
// Reference grouping preserved exactly:
//   out(2d,2h)     = A
//   out(2d,2h+1)   = 0.5(A+B)
//   out(2d+1,2h)   = 0.5(A+C)
//   out(2d+1,2h+1) = 0.5(0.5(A+C) + 0.5(B+D))
// then w-odd applies 0.5(y[w] + y[w+1]) last. avg(x,x)==x exactly, so even
// lanes use a duplicated second index instead of a branch.

#define DV 80
#define HV 96
#define WV 112
#define ROW4 (WV * 4)          // 448 float4 per input row
#define OROW4 (2 * WV * 4)     // 896 float4 per output row

__device__ __forceinline__ float4 avg4(float4 x, float4 y) {
    return make_float4(0.5f * (x.x + y.x), 0.5f * (x.y + y.y),
                       0.5f * (x.z + y.z), 0.5f * (x.w + y.w));
}

__global__ __launch_bounds__(896) void UpsampleInterp_kernel(
        const float4* __restrict__ in, float4* __restrict__ out) {
    const int h0 = blockIdx.x;             // 0..95
    const int d0 = blockIdx.y;             // 0..79
    const int t  = threadIdx.x;            // 0..895
    const int c4 = t & 3;                  // channel quad
    const int wo = t >> 2;                 // 0..223
    const int wi = wo >> 1;                // 0..111
    const int wodd = wo & 1;
    const int wib = (wi + 1 < WV) ? wi + 1 : WV - 1;
    const int i1 = wodd ? wib : wi;        // duplicate for even lanes

    const int d1 = (d0 + 1 < DV) ? d0 + 1 : DV - 1;  // block-uniform
    const int h1 = (h0 + 1 < HV) ? h0 + 1 : HV - 1;  // block-uniform

    const int baseA = (d0 * HV + h0) * ROW4 + c4;
    const int baseB = (d0 * HV + h1) * ROW4 + c4;
    const int baseC = (d1 * HV + h0) * ROW4 + c4;
    const int baseD = (d1 * HV + h1) * ROW4 + c4;

    // 8 independent loads (L1 serves the 2-lane duplicates)
    const float4 A0 = in[baseA + 4 * wi], A1 = in[baseA + 4 * i1];
    const float4 B0 = in[baseB + 4 * wi], B1 = in[baseB + 4 * i1];
    const float4 C0 = in[baseC + 4 * wi], C1 = in[baseC + 4 * i1];
    const float4 D0 = in[baseD + 4 * wi], D1 = in[baseD + 4 * i1];

    const float4 ab0 = avg4(A0, B0), ab1 = avg4(A1, B1);
    const float4 ac0 = avg4(A0, C0), ac1 = avg4(A1, C1);
    const float4 bd0 = avg4(B0, D0), bd1 = avg4(B1, D1);

    const float4 r00 = avg4(A0, A1);
    const float4 r01 = avg4(ab0, ab1);
    const float4 r10 = avg4(ac0, ac1);
    const float4 r11 = avg4(avg4(ac0, bd0), avg4(ac1, bd1));

    // 4 contiguous row stores
    const int ob = ((2 * d0) * (2 * HV) + (2 * h0)) * OROW4 + t;
    out[ob]                     = r00;   // (2d0,   2h0)
    out[ob + OROW4]             = r01;   // (2d0,   2h0+1)
    out[ob + (2 * HV) * OROW4]          = r10;   // (2d0+1, 2h0)
    out[ob + (2 * HV) * OROW4 + OROW4]  = r11;   // (2d0+1, 2h0+1)
}

extern "C" void kernel_launch(void* const* d_in, const int* in_sizes, int n_in,
                              void* d_out, int out_size, void* d_ws, size_t ws_size,
                              hipStream_t stream) {
    const float4* in = (const float4*)d_in[0];
    float4* out = (float4*)d_out;
    dim3 grid(HV, DV);  // (h0, d0) = (96, 80)
    UpsampleInterp_kernel<<<grid, 896, 0, stream>>>(in, out);
}